// Round 8
// baseline (195.000 us; speedup 1.0000x reference)
//
#include <hip/hip_runtime.h>
#include <cmath>

namespace {
constexpr int BN = 1024;
constexpr int NC = 96;
constexpr int MT = 256;
constexpr int UL = 40;
constexpr int LS = 81;     // 2*UL+1 states
constexpr int PAIRS = 41;  // pairs per row (lane i -> states 2i, 2i+1)
constexpr int PADP = 44;   // padded row stride (44 dwords = 176 B, uint4-aligned)

template <int CTRL>
__device__ __forceinline__ float dppf(float v) {
  return __builtin_bit_cast(
      float, __builtin_amdgcn_update_dpp(0, __builtin_bit_cast(int, v), CTRL,
                                         0xf, 0xf, true));
}
__device__ __forceinline__ float rl63(float x) {
  return __builtin_bit_cast(
      float, __builtin_amdgcn_readlane(__builtin_bit_cast(int, x), 63));
}
__device__ __forceinline__ float wave_sum(float x) {
  x += dppf<0x111>(x);
  x += dppf<0x112>(x);
  x += dppf<0x114>(x);
  x += dppf<0x118>(x);
  x += dppf<0x142>(x);
  x += dppf<0x143>(x);
  return rl63(x);
}
// lane i <- lane i-1 (lane 0 <- 0)
__device__ __forceinline__ float wave_shr1(float v) { return dppf<0x138>(v); }
__device__ __forceinline__ float fast_rcp(float x) {
  return __builtin_amdgcn_rcpf(x);
}
__device__ __forceinline__ unsigned packu(float a, float b) {
  unsigned ua = __builtin_bit_cast(unsigned, a) >> 16;
  unsigned ub = __builtin_bit_cast(unsigned, b) & 0xffff0000u;
  return ua | ub;
}
__device__ __forceinline__ float bf_lo(unsigned u) {
  return __builtin_bit_cast(float, u << 16);
}
__device__ __forceinline__ float bf_hi(unsigned u) {
  return __builtin_bit_cast(float, u & 0xffff0000u);
}

constexpr float FQ = 1e8f;      // block-start row scale
constexpr float SEPS = 1e-30f;  // rcp-input floor (NaN-proof)

// One wave per (item, phase). Lane i owns states s=2i, 2i+1.
// DEFERRED-SUM scheme (verified round 3) + COALESCED [b][t][pair] stores
// (verified round 7; the store-ack wall fix). Round 8 additions:
//  - row stride padded to 44 dwords; lanes 41..43 store ZEROS to the pad
//    (workspace is poisoned between runs — pads must be explicitly zeroed)
//    so combine can read aligned uint4 vectors.
//  - main loop unrolled x2: two burst scopes -> two ob register sets ->
//    block n's store-acks drain under block n+1's compute.
__global__ __launch_bounds__(64) void chain_kernel(
    const float* __restrict__ gout, const int* __restrict__ glabel,
    const int* __restrict__ gw, unsigned* __restrict__ xa,
    unsigned* __restrict__ xb) {
  const int bx = blockIdx.x;
  const int b = bx >> 1, ph = bx & 1;
  const int i = threadIdx.x;
  const float* P = gout + (size_t)b * (NC * MT);  // P[c*MT + t]
  const int* lab = glabel + b * UL;
  const int T = gw[b] >> 2;  // [128,256]

  const int s0 = 2 * i, s1 = s0 + 1;
  const float h0f = (i <= 40) ? 1.f : 0.f;
  const float h1f = (i <= 39) ? 1.f : 0.f;
  const int iw = (i <= 40) ? i : 40;
  const bool act = (i <= 40);    // real pair lanes
  const bool actw = (i <= 43);   // store lanes (41..43 write pad zeros)

  const float* pB;
  const float* pL;
  float mskf;
  unsigned* outp;  // points at [b][0][col] in the [b][t][pad-pair] layout
  if (ph == 0) {  // alpha
    const int li = (i < UL) ? lab[i] : 0;
    const int lm = (i >= 1 && i < UL) ? lab[i - 1] : 0;
    pB = P;
    pL = P + (size_t)li * MT;
    mskf = (i >= 1 && i <= 39 && li != lm) ? 1.f : 0.f;
    const int col = act ? iw : i;  // lanes 41..43 -> pad cols 41..43
    outp = xa + (size_t)b * MT * PADP + col;
  } else {  // beta: class-flipped probs, reversed labels
    const int rli = (i < UL) ? lab[UL - 1 - i] : 0;
    const int rlm = (i >= 1 && i < UL) ? lab[UL - i] : 0;
    pB = P + (size_t)(NC - 1) * MT;
    pL = P + (size_t)(NC - 1 - rli) * MT;
    mskf = (i >= 1 && i <= 39 && rli != rlm) ? 1.f : 0.f;
    const int col = act ? (40 - iw) : i;  // pair-reversed; pads at 41..43
    outp = xb + (size_t)b * MT * PADP + col;
  }

  // ---- prob pipeline: current block unpacked, next block in flight ----
  float pbv[8], plv[8];
  float4 LA = *(const float4*)(pB + 0), LB = *(const float4*)(pB + 4);
  float4 MA = *(const float4*)(pL + 0), MB = *(const float4*)(pL + 4);
  pbv[0] = LA.x; pbv[1] = LA.y; pbv[2] = LA.z; pbv[3] = LA.w;
  pbv[4] = LB.x; pbv[5] = LB.y; pbv[6] = LB.z; pbv[7] = LB.w;
  plv[0] = MA.x; plv[1] = MA.y; plv[2] = MA.z; plv[3] = MA.w;
  plv[4] = MB.x; plv[5] = MB.y; plv[6] = MB.z; plv[7] = MB.w;
  LA = *(const float4*)(pB + 8); LB = *(const float4*)(pB + 12);
  MA = *(const float4*)(pL + 8); MB = *(const float4*)(pL + 12);

  // ---- t = 0 ----
  float v0 = (i == 0) ? pbv[0] : 0.f;
  float v1 = (i == 0) ? plv[0] : 0.f;

  float f0[8], f1[8], sv[8];  // 8-step row buffer + per-lane row totals
  if (ph == 0) {
    sv[0] = v0 + v1;               // raw scale matches x=1 convention
    f0[0] = (i == 0) ? 1.f : 0.f;  // x = a_raw/p at t=0
    f1[0] = f0[0];
    v0 *= FQ;
    v1 *= FQ;
  } else {
    v0 *= FQ;
    v1 *= FQ;
    sv[0] = v0 + v1;
    f0[0] = v0;
    f1[0] = 0.f;  // overwritten by step k=1's pm1 (same scale)
  }

#define CTC_STEP(T_, K_, DOMASK)                                      \
  {                                                                   \
    float pm1 = wave_shr1(v1);                                        \
    if (ph == 1 && (K_) >= 1) f1[(K_)-1] = pm1;                       \
    float u0 = v0 + pm1;                                              \
    float u1 = (v0 + v1) + pm1 * mskf;                                \
    if (DOMASK) {                                                     \
      const int start_ = LS - 2 * (T - (T_));                         \
      if (s0 < start_) u0 = 0.f;                                      \
      if (s1 < start_) u1 = 0.f;                                      \
    }                                                                 \
    const float x0 = u0 * h0f, x1 = u1 * h1f;                         \
    float n0 = x0 * pbv[(K_)];                                        \
    float n1 = x1 * plv[(K_)];                                        \
    sv[(K_)] = n0 + n1;                                               \
    v0 = n0; v1 = n1;                                                 \
    if (ph == 0) { f0[(K_)] = x0; f1[(K_)] = x1; }                    \
    else { f0[(K_)] = n0; }                                           \
  }

  // 8 independent wave-sums, breadth-first: 8-way ILP on the DPP trees.
#define WS_LEVEL(CTRL)                                                \
  {                                                                   \
    _Pragma("unroll")                                                 \
    for (int k = 0; k < 8; ++k) sv[k] += dppf<CTRL>(sv[k]);           \
  }

#define CTC_BURST(T0_)                                                \
  {                                                                   \
    if (ph == 1) f1[7] = wave_shr1(v1); /* before rescale! */         \
    WS_LEVEL(0x111) WS_LEVEL(0x112) WS_LEVEL(0x114)                   \
    WS_LEVEL(0x118) WS_LEVEL(0x142) WS_LEVEL(0x143)                   \
    _Pragma("unroll")                                                 \
    for (int k = 0; k < 8; ++k) sv[k] = rl63(sv[k]);                  \
    if (actw) {                                                       \
      unsigned ob[8];                                                 \
      _Pragma("unroll")                                               \
      for (int k = 0; k < 8; ++k) {                                   \
        float inv = fast_rcp(fmaxf(sv[k], SEPS));                     \
        ob[k] = act ? packu(f0[k] * inv, f1[k] * inv) : 0u;           \
      }                                                               \
      if ((T0_) + 7 < T) {                                            \
        _Pragma("unroll")                                             \
        for (int k = 0; k < 8; ++k)                                   \
          outp[((T0_) + k) * PADP] = ob[k];  /* wave-coalesced */     \
      } else {                                                        \
        _Pragma("unroll")                                             \
        for (int k = 0; k < 8; ++k)                                   \
          if ((T0_) + k < T) outp[((T0_) + k) * PADP] = ob[k];        \
      }                                                               \
    }                                                                 \
    float rb = FQ * fast_rcp(fmaxf(sv[7], SEPS));                     \
    rb = fminf(fmaxf(rb, 1e-20f), 1e20f);                             \
    v0 *= rb; v1 *= rb;                                               \
  }

#define CTC_UNPACK(T0_)                                               \
  {                                                                   \
    pbv[0] = LA.x; pbv[1] = LA.y; pbv[2] = LA.z; pbv[3] = LA.w;       \
    pbv[4] = LB.x; pbv[5] = LB.y; pbv[6] = LB.z; pbv[7] = LB.w;       \
    plv[0] = MA.x; plv[1] = MA.y; plv[2] = MA.z; plv[3] = MA.w;       \
    plv[4] = MB.x; plv[5] = MB.y; plv[6] = MB.z; plv[7] = MB.w;       \
    int np = (T0_) + 8;                                               \
    if (np > 248) np = 248;                                           \
    LA = *(const float4*)(pB + np); LB = *(const float4*)(pB + np + 4); \
    MA = *(const float4*)(pL + np); MB = *(const float4*)(pL + np + 4); \
  }

  // ---- prologue: steps 1..7, rows 0..7 (T>=128 -> unmasked) ----
#pragma unroll
  for (int k = 1; k < 8; ++k) CTC_STEP(k, k, false);
  CTC_BURST(0);

  // ---- main: x2-unrolled unmasked fast path (t0+15 <= T-41) ----
  int t0 = 8;
  for (; t0 + 55 < T; t0 += 16) {
    CTC_UNPACK(t0);
#pragma unroll
    for (int k = 0; k < 8; ++k) CTC_STEP(t0 + k, k, false);
    CTC_BURST(t0);
    CTC_UNPACK(t0 + 8);
#pragma unroll
    for (int k = 0; k < 8; ++k) CTC_STEP(t0 + 8 + k, k, false);
    CTC_BURST(t0 + 8);
  }
  // ---- single unmasked blocks (t0+7 <= T-41) ----
  for (; t0 + 47 < T; t0 += 8) {
    CTC_UNPACK(t0);
#pragma unroll
    for (int k = 0; k < 8; ++k) CTC_STEP(t0 + k, k, false);
    CTC_BURST(t0);
  }
  // ---- tail: masked blocks ----
  for (; t0 < T; t0 += 8) {
    CTC_UNPACK(t0);
#pragma unroll
    for (int k = 0; k < 8; ++k) CTC_STEP(t0 + k, k, true);
    CTC_BURST(t0);
  }
#undef CTC_STEP
#undef CTC_BURST
#undef CTC_UNPACK
#undef WS_LEVEL
}

// Fully parallel combine: block = item, thread = t. Rows are contiguous
// 176-B (11 x uint4) runs, uint4-aligned thanks to PADP=44; pad columns are
// zero so they contribute nothing. lh_t = sum_p x'[t][p] * b'[T-1-t][p].
__global__ __launch_bounds__(256) void combine_kernel(
    const int* __restrict__ gw, const unsigned* __restrict__ xa,
    const unsigned* __restrict__ xb, float* __restrict__ loss_out) {
  const int b = blockIdx.x;
  const int tid = threadIdx.x;
  const int T = gw[b] >> 2;
  float lsum = 0.f;
  if (tid < T) {
    const uint4* A4 =
        (const uint4*)(xa + ((size_t)b * MT + tid) * PADP);
    const uint4* B4 =
        (const uint4*)(xb + ((size_t)b * MT + (T - 1 - tid)) * PADP);
    float d = 0.f;
#pragma unroll
    for (int j = 0; j < 11; ++j) {
      const uint4 av = A4[j];
      const uint4 bv = B4[j];
      d = fmaf(bf_lo(av.x), bf_lo(bv.x), d);
      d = fmaf(bf_hi(av.x), bf_hi(bv.x), d);
      d = fmaf(bf_lo(av.y), bf_lo(bv.y), d);
      d = fmaf(bf_hi(av.y), bf_hi(bv.y), d);
      d = fmaf(bf_lo(av.z), bf_lo(bv.z), d);
      d = fmaf(bf_hi(av.z), bf_hi(bv.z), d);
      d = fmaf(bf_lo(av.w), bf_lo(bv.w), d);
      d = fmaf(bf_hi(av.w), bf_hi(bv.w), d);
    }
    lsum = -__logf(fmaxf(d, 1e-37f));
  }
  lsum = wave_sum(lsum);
  __shared__ float part[4];
  if ((tid & 63) == 0) part[tid >> 6] = lsum;
  __syncthreads();
  if (tid == 0) {
    float L = part[0] + part[1] + part[2] + part[3];
    loss_out[b] = fminf(fmaxf(L, -1e30f), 1e30f);  // fmin/fmax absorb NaN
  }
}

__global__ void reduce_kernel(const float* __restrict__ loss_in,
                              float* __restrict__ out) {
  __shared__ double sm[256];
  const int tid = threadIdx.x;
  double s = 0.0;
  for (int k = tid; k < BN; k += 256) s += (double)loss_in[k];
  sm[tid] = s;
  __syncthreads();
  for (int w = 128; w >= 1; w >>= 1) {
    if (tid < w) sm[tid] += sm[tid + w];
    __syncthreads();
  }
  if (tid == 0) out[0] = (float)sm[0];
}
}  // namespace

extern "C" void kernel_launch(void* const* d_in, const int* in_sizes, int n_in,
                              void* d_out, int out_size, void* d_ws, size_t ws_size,
                              hipStream_t stream) {
  const float* gout = (const float*)d_in[0];
  const int* glabel = (const int*)d_in[1];
  const int* gw = (const int*)d_in[2];
  unsigned* xa = (unsigned*)d_ws;                  // BN*MT*PADP uints (46 MB)
  unsigned* xb = xa + (size_t)BN * MT * PADP;      // 46 MB
  float* loss = (float*)(xb + (size_t)BN * MT * PADP);  // 4 KB
  chain_kernel<<<2 * BN, 64, 0, stream>>>(gout, glabel, gw, xa, xb);
  combine_kernel<<<BN, 256, 0, stream>>>(gw, xa, xb, loss);
  reduce_kernel<<<1, 256, 0, stream>>>(loss, (float*)d_out);
}

// Round 9
// 183.342 us; speedup vs baseline: 1.0636x; 1.0636x over previous
//
#include <hip/hip_runtime.h>
#include <cmath>

namespace {
constexpr int BN = 1024;
constexpr int NC = 96;
constexpr int MT = 256;
constexpr int UL = 40;
constexpr int LS = 81;     // 2*UL+1 states
constexpr int PAIRS = 41;  // pairs per row (lane i -> states 2i, 2i+1)

template <int CTRL>
__device__ __forceinline__ float dppf(float v) {
  return __builtin_bit_cast(
      float, __builtin_amdgcn_update_dpp(0, __builtin_bit_cast(int, v), CTRL,
                                         0xf, 0xf, true));
}
__device__ __forceinline__ float rl63(float x) {
  return __builtin_bit_cast(
      float, __builtin_amdgcn_readlane(__builtin_bit_cast(int, x), 63));
}
__device__ __forceinline__ float wave_sum(float x) {
  x += dppf<0x111>(x);
  x += dppf<0x112>(x);
  x += dppf<0x114>(x);
  x += dppf<0x118>(x);
  x += dppf<0x142>(x);
  x += dppf<0x143>(x);
  return rl63(x);
}
// lane i <- lane i-1 (lane 0 <- 0)
__device__ __forceinline__ float wave_shr1(float v) { return dppf<0x138>(v); }
__device__ __forceinline__ float fast_rcp(float x) {
  return __builtin_amdgcn_rcpf(x);
}
__device__ __forceinline__ unsigned packu(float a, float b) {
  unsigned ua = __builtin_bit_cast(unsigned, a) >> 16;
  unsigned ub = __builtin_bit_cast(unsigned, b) & 0xffff0000u;
  return ua | ub;
}
__device__ __forceinline__ float bf_lo(unsigned u) {
  return __builtin_bit_cast(float, u << 16);
}
__device__ __forceinline__ float bf_hi(unsigned u) {
  return __builtin_bit_cast(float, u & 0xffff0000u);
}

constexpr float FQ = 1e8f;       // block-start row scale
constexpr float SEPS = 1e-30f;   // rcp-input floor (NaN-proof)
constexpr float GB = 1099511627776.0f;  // 2^40 mid-block boost (EXACT in fp32)

// One wave per (item, phase). Lane i owns states s=2i, 2i+1.
// DEFERRED-SUM scheme (verified round 3) + COALESCED [b][t][pair] stores
// (verified round 7). Round 9: 16-STEP BLOCKS — same depth-1 prefetch
// schedule, but each round's compute doubles so the 64-line pL-gather
// latency is fully covered, and the number of latency exposures halves
// (32 -> 16 at T=256). Mid-block numerical guard: after step 8's pm1
// capture, v is boosted by G=2^40 (exact power-of-2, zero rounding); rows
// >= 8 carry G uniformly, each row is normalized by its OWN raw sum at pack
// time (G cancels), block-end deadbeat rb = FQ/sv[15] absorbs it.
__global__ __launch_bounds__(64) void chain_kernel(
    const float* __restrict__ gout, const int* __restrict__ glabel,
    const int* __restrict__ gw, unsigned* __restrict__ xa,
    unsigned* __restrict__ xb) {
  const int bx = blockIdx.x;
  const int b = bx >> 1, ph = bx & 1;
  const int i = threadIdx.x;
  const float* P = gout + (size_t)b * (NC * MT);  // P[c*MT + t]
  const int* lab = glabel + b * UL;
  const int T = gw[b] >> 2;  // [128,256]

  const int s0 = 2 * i, s1 = s0 + 1;
  const float h0f = (i <= 40) ? 1.f : 0.f;
  const float h1f = (i <= 39) ? 1.f : 0.f;
  const int iw = (i <= 40) ? i : 40;
  const bool act = (i <= 40);

  const float* pB;
  const float* pL;
  float mskf;
  unsigned* outp;  // points at [b][0][col] in the [b][t][pair] layout
  if (ph == 0) {  // alpha
    const int li = (i < UL) ? lab[i] : 0;
    const int lm = (i >= 1 && i < UL) ? lab[i - 1] : 0;
    pB = P;
    pL = P + (size_t)li * MT;
    mskf = (i >= 1 && i <= 39 && li != lm) ? 1.f : 0.f;
    outp = xa + (size_t)b * MT * PAIRS + iw;
  } else {  // beta: class-flipped probs, reversed labels
    const int rli = (i < UL) ? lab[UL - 1 - i] : 0;
    const int rlm = (i >= 1 && i < UL) ? lab[UL - i] : 0;
    pB = P + (size_t)(NC - 1) * MT;
    pL = P + (size_t)(NC - 1 - rli) * MT;
    mskf = (i >= 1 && i <= 39 && rli != rlm) ? 1.f : 0.f;
    outp = xb + (size_t)b * MT * PAIRS + (40 - iw);  // pair-reversed column
  }

  // ---- prob pipeline: current 16-step block unpacked, next in flight ----
  float pbv[16], plv[16];
  float4 LA = *(const float4*)(pB + 0),  LB = *(const float4*)(pB + 4);
  float4 LC = *(const float4*)(pB + 8),  LD = *(const float4*)(pB + 12);
  float4 MA = *(const float4*)(pL + 0),  MB = *(const float4*)(pL + 4);
  float4 MC = *(const float4*)(pL + 8),  MD = *(const float4*)(pL + 12);
  pbv[0] = LA.x;  pbv[1] = LA.y;  pbv[2] = LA.z;  pbv[3] = LA.w;
  pbv[4] = LB.x;  pbv[5] = LB.y;  pbv[6] = LB.z;  pbv[7] = LB.w;
  pbv[8] = LC.x;  pbv[9] = LC.y;  pbv[10] = LC.z; pbv[11] = LC.w;
  pbv[12] = LD.x; pbv[13] = LD.y; pbv[14] = LD.z; pbv[15] = LD.w;
  plv[0] = MA.x;  plv[1] = MA.y;  plv[2] = MA.z;  plv[3] = MA.w;
  plv[4] = MB.x;  plv[5] = MB.y;  plv[6] = MB.z;  plv[7] = MB.w;
  plv[8] = MC.x;  plv[9] = MC.y;  plv[10] = MC.z; plv[11] = MC.w;
  plv[12] = MD.x; plv[13] = MD.y; plv[14] = MD.z; plv[15] = MD.w;
  LA = *(const float4*)(pB + 16); LB = *(const float4*)(pB + 20);
  LC = *(const float4*)(pB + 24); LD = *(const float4*)(pB + 28);
  MA = *(const float4*)(pL + 16); MB = *(const float4*)(pL + 20);
  MC = *(const float4*)(pL + 24); MD = *(const float4*)(pL + 28);

  // ---- t = 0 ----
  float v0 = (i == 0) ? pbv[0] : 0.f;
  float v1 = (i == 0) ? plv[0] : 0.f;

  float f0[16], f1[16], sv[16];  // 16-step row buffer + per-lane row totals
  if (ph == 0) {
    sv[0] = v0 + v1;               // raw scale matches x=1 convention
    f0[0] = (i == 0) ? 1.f : 0.f;  // x = a_raw/p at t=0
    f1[0] = f0[0];
    v0 *= FQ;
    v1 *= FQ;
  } else {
    v0 *= FQ;
    v1 *= FQ;
    sv[0] = v0 + v1;
    f0[0] = v0;
    f1[0] = 0.f;  // overwritten by step k=1's pm1 (same scale)
  }

// BOOST: 1 at k==8 (v,pm1 scaled by 2^40 AFTER pm1 capture so row 7's beta
// f1 slot stays at row-7 scale), else 0.
#define CTC_STEP(T_, K_, DOMASK, BOOST)                               \
  {                                                                   \
    float pm1 = wave_shr1(v1);                                        \
    if (ph == 1 && (K_) >= 1) f1[(K_)-1] = pm1;                       \
    if (BOOST) { v0 *= GB; v1 *= GB; pm1 *= GB; }                     \
    float u0 = v0 + pm1;                                              \
    float u1 = (v0 + v1) + pm1 * mskf;                                \
    if (DOMASK) {                                                     \
      const int start_ = LS - 2 * (T - (T_));                         \
      if (s0 < start_) u0 = 0.f;                                      \
      if (s1 < start_) u1 = 0.f;                                      \
    }                                                                 \
    const float x0 = u0 * h0f, x1 = u1 * h1f;                         \
    float n0 = x0 * pbv[(K_)];                                        \
    float n1 = x1 * plv[(K_)];                                        \
    sv[(K_)] = n0 + n1;                                               \
    v0 = n0; v1 = n1;                                                 \
    if (ph == 0) { f0[(K_)] = x0; f1[(K_)] = x1; }                    \
    else { f0[(K_)] = n0; }                                           \
  }

  // 16 independent wave-sums, breadth-first: 16-way ILP on the DPP trees.
#define WS_LEVEL(CTRL)                                                \
  {                                                                   \
    _Pragma("unroll")                                                 \
    for (int k = 0; k < 16; ++k) sv[k] += dppf<CTRL>(sv[k]);          \
  }

#define CTC_BURST(T0_)                                                \
  {                                                                   \
    if (ph == 1) f1[15] = wave_shr1(v1); /* before rescale! */        \
    WS_LEVEL(0x111) WS_LEVEL(0x112) WS_LEVEL(0x114)                   \
    WS_LEVEL(0x118) WS_LEVEL(0x142) WS_LEVEL(0x143)                   \
    _Pragma("unroll")                                                 \
    for (int k = 0; k < 16; ++k) sv[k] = rl63(sv[k]);                 \
    if (act) {                                                        \
      unsigned ob[16];                                                \
      _Pragma("unroll")                                               \
      for (int k = 0; k < 16; ++k) {                                  \
        float inv = fast_rcp(fmaxf(sv[k], SEPS));                     \
        ob[k] = packu(f0[k] * inv, f1[k] * inv);                      \
      }                                                               \
      if ((T0_) + 15 < T) {                                           \
        _Pragma("unroll")                                             \
        for (int k = 0; k < 16; ++k)                                  \
          outp[((T0_) + k) * PAIRS] = ob[k];  /* wave-coalesced */    \
      } else {                                                        \
        _Pragma("unroll")                                             \
        for (int k = 0; k < 16; ++k)                                  \
          if ((T0_) + k < T) outp[((T0_) + k) * PAIRS] = ob[k];       \
      }                                                               \
    }                                                                 \
    float rb = FQ * fast_rcp(fmaxf(sv[15], SEPS));                    \
    rb = fminf(fmaxf(rb, 1e-20f), 1e20f);                             \
    v0 *= rb; v1 *= rb;                                               \
  }

#define CTC_UNPACK(T0_)                                               \
  {                                                                   \
    pbv[0] = LA.x;  pbv[1] = LA.y;  pbv[2] = LA.z;  pbv[3] = LA.w;    \
    pbv[4] = LB.x;  pbv[5] = LB.y;  pbv[6] = LB.z;  pbv[7] = LB.w;    \
    pbv[8] = LC.x;  pbv[9] = LC.y;  pbv[10] = LC.z; pbv[11] = LC.w;   \
    pbv[12] = LD.x; pbv[13] = LD.y; pbv[14] = LD.z; pbv[15] = LD.w;   \
    plv[0] = MA.x;  plv[1] = MA.y;  plv[2] = MA.z;  plv[3] = MA.w;    \
    plv[4] = MB.x;  plv[5] = MB.y;  plv[6] = MB.z;  plv[7] = MB.w;    \
    plv[8] = MC.x;  plv[9] = MC.y;  plv[10] = MC.z; plv[11] = MC.w;   \
    plv[12] = MD.x; plv[13] = MD.y; plv[14] = MD.z; plv[15] = MD.w;   \
    int np = (T0_) + 16;                                              \
    if (np > 240) np = 240;                                           \
    LA = *(const float4*)(pB + np);      LB = *(const float4*)(pB + np + 4);  \
    LC = *(const float4*)(pB + np + 8);  LD = *(const float4*)(pB + np + 12); \
    MA = *(const float4*)(pL + np);      MB = *(const float4*)(pL + np + 4);  \
    MC = *(const float4*)(pL + np + 8);  MD = *(const float4*)(pL + np + 12); \
  }

  // ---- prologue: steps 1..15, rows 0..15 (T>=128 -> unmasked) ----
#pragma unroll
  for (int k = 1; k < 8; ++k) CTC_STEP(k, k, false, 0);
  CTC_STEP(8, 8, false, 1);
#pragma unroll
  for (int k = 9; k < 16; ++k) CTC_STEP(k, k, false, 0);
  CTC_BURST(0);

  // ---- main: unmasked fast path (t0+15 <= T-41) ----
  int t0 = 16;
  for (; t0 + 56 <= T; t0 += 16) {
    CTC_UNPACK(t0);
#pragma unroll
    for (int k = 0; k < 8; ++k) CTC_STEP(t0 + k, k, false, 0);
    CTC_STEP(t0 + 8, 8, false, 1);
#pragma unroll
    for (int k = 9; k < 16; ++k) CTC_STEP(t0 + k, k, false, 0);
    CTC_BURST(t0);
  }
  // ---- tail: masked blocks ----
  for (; t0 < T; t0 += 16) {
    CTC_UNPACK(t0);
#pragma unroll
    for (int k = 0; k < 8; ++k) CTC_STEP(t0 + k, k, true, 0);
    CTC_STEP(t0 + 8, 8, true, 1);
#pragma unroll
    for (int k = 9; k < 16; ++k) CTC_STEP(t0 + k, k, true, 0);
    CTC_BURST(t0);
  }
#undef CTC_STEP
#undef CTC_BURST
#undef CTC_UNPACK
#undef WS_LEVEL
}

// Fully parallel combine: block = item, thread = t. With the [b][t][pair]
// layout each thread's two rows are CONTIGUOUS 41-dword runs; adjacent
// threads read adjacent rows -> wave-level streams coalesce. lh_t =
// sum_p x'[t][p] * b'[T-1-t][p]; rows pre-normalized at store.
__global__ __launch_bounds__(256) void combine_kernel(
    const int* __restrict__ gw, const unsigned* __restrict__ xa,
    const unsigned* __restrict__ xb, float* __restrict__ loss_out) {
  const int b = blockIdx.x;
  const int tid = threadIdx.x;
  const int T = gw[b] >> 2;
  float lsum = 0.f;
  if (tid < T) {
    const unsigned* A = xa + ((size_t)b * MT + tid) * PAIRS;
    const unsigned* Bb = xb + ((size_t)b * MT + (T - 1 - tid)) * PAIRS;
    float d = 0.f;
#pragma unroll
    for (int p = 0; p < PAIRS; ++p) {
      const unsigned av = A[p];
      const unsigned bv = Bb[p];
      d = fmaf(bf_lo(av), bf_lo(bv), d);
      d = fmaf(bf_hi(av), bf_hi(bv), d);
    }
    lsum = -__logf(fmaxf(d, 1e-37f));
  }
  lsum = wave_sum(lsum);
  __shared__ float part[4];
  if ((tid & 63) == 0) part[tid >> 6] = lsum;
  __syncthreads();
  if (tid == 0) {
    float L = part[0] + part[1] + part[2] + part[3];
    loss_out[b] = fminf(fmaxf(L, -1e30f), 1e30f);  // fmin/fmax absorb NaN
  }
}

__global__ void reduce_kernel(const float* __restrict__ loss_in,
                              float* __restrict__ out) {
  __shared__ double sm[256];
  const int tid = threadIdx.x;
  double s = 0.0;
  for (int k = tid; k < BN; k += 256) s += (double)loss_in[k];
  sm[tid] = s;
  __syncthreads();
  for (int w = 128; w >= 1; w >>= 1) {
    if (tid < w) sm[tid] += sm[tid + w];
    __syncthreads();
  }
  if (tid == 0) out[0] = (float)sm[0];
}
}  // namespace

extern "C" void kernel_launch(void* const* d_in, const int* in_sizes, int n_in,
                              void* d_out, int out_size, void* d_ws, size_t ws_size,
                              hipStream_t stream) {
  const float* gout = (const float*)d_in[0];
  const int* glabel = (const int*)d_in[1];
  const int* gw = (const int*)d_in[2];
  unsigned* xa = (unsigned*)d_ws;                  // BN*MT*PAIRS uints (43 MB)
  unsigned* xb = xa + (size_t)BN * MT * PAIRS;     // 43 MB
  float* loss = (float*)(xb + (size_t)BN * MT * PAIRS);  // 4 KB
  chain_kernel<<<2 * BN, 64, 0, stream>>>(gout, glabel, gw, xa, xb);
  combine_kernel<<<BN, 256, 0, stream>>>(gw, xa, xb, loss);
  reduce_kernel<<<1, 256, 0, stream>>>(loss, (float*)d_out);
}